// Round 1
// baseline (7412.225 us; speedup 1.0000x reference)
//
#include <hip/hip_runtime.h>
#include <math.h>

#define STEPS 19
#define NEG_SLOPE 0.01f
#define THREADS 256

__device__ __forceinline__ float lrelu(float x) {
    return x >= 0.0f ? x : NEG_SLOPE * x;
}

__device__ __forceinline__ float sigm(float x) {
    // 1/(1+exp(-x)): v_exp_f32 + v_rcp_f32, ~1-2 ulp, far inside 1e-2 threshold
    return __builtin_amdgcn_rcpf(1.0f + __expf(-x));
}

__global__ __launch_bounds__(THREADS) void recurrent_kernel(
    const float* __restrict__ w,
    const float* __restrict__ Wh1, const float* __restrict__ bh1,
    const float* __restrict__ Wh2, const float* __restrict__ bh2,
    const float* __restrict__ Wh3, const float* __restrict__ bh3,
    const float* __restrict__ Wz1, const float* __restrict__ bz1,
    const float* __restrict__ Wz2, const float* __restrict__ bz2,
    const float* __restrict__ Wz3, const float* __restrict__ bz3,
    float* __restrict__ out, int nrows)
{
    // All weights staged to LDS once per block; reads are wave-uniform broadcasts.
    __shared__ float sWh1[100]; __shared__ float sbh1[50];
    __shared__ float sWh2[1000]; __shared__ float sbh2[20];
    __shared__ float sWh3[40];  __shared__ float sbh3[2];
    __shared__ float sWz1[100]; __shared__ float sbz1[50];
    __shared__ float sWz2[1000]; __shared__ float sbz2[20];
    __shared__ float sWz3[40];  __shared__ float sbz3[2];

    const int t = threadIdx.x;
    for (int i = t; i < 100;  i += THREADS) sWh1[i] = Wh1[i];
    for (int i = t; i < 50;   i += THREADS) sbh1[i] = bh1[i];
    for (int i = t; i < 1000; i += THREADS) sWh2[i] = Wh2[i];
    for (int i = t; i < 20;   i += THREADS) sbh2[i] = bh2[i];
    for (int i = t; i < 40;   i += THREADS) sWh3[i] = Wh3[i];
    for (int i = t; i < 2;    i += THREADS) sbh3[i] = bh3[i];
    for (int i = t; i < 100;  i += THREADS) sWz1[i] = Wz1[i];
    for (int i = t; i < 50;   i += THREADS) sbz1[i] = bz1[i];
    for (int i = t; i < 1000; i += THREADS) sWz2[i] = Wz2[i];
    for (int i = t; i < 20;   i += THREADS) sbz2[i] = bz2[i];
    for (int i = t; i < 40;   i += THREADS) sWz3[i] = Wz3[i];
    for (int i = t; i < 2;    i += THREADS) sbz3[i] = bz3[i];
    __syncthreads();

    const int row = blockIdx.x * THREADS + t;
    if (row >= nrows) return;

    // initial carry h = w[row]
    const float2 w2 = *(const float2*)(w + 2 * (size_t)row);
    float h0 = w2.x, h1 = w2.y;

    float* __restrict__ orow = out + (size_t)row * (STEPS * 2);

    for (int s = 0; s < STEPS; ++s) {
        // ---- h path ----
        // layer h1: [2] -> [50], lrelu.  Wh1 row-major [2][50].
        float a1[50];
        #pragma unroll
        for (int j = 0; j < 50; ++j) {
            float v = fmaf(h1, sWh1[50 + j], fmaf(h0, sWh1[j], sbh1[j]));
            a1[j] = lrelu(v);
        }
        // layer h2: [50] -> [20], lrelu.  Wh2 row-major [50][20].
        float a2[20];
        #pragma unroll
        for (int i = 0; i < 20; ++i) a2[i] = sbh2[i];
        #pragma unroll
        for (int k = 0; k < 50; ++k) {
            const float av = a1[k];
            #pragma unroll
            for (int i = 0; i < 20; ++i) a2[i] = fmaf(av, sWh2[k * 20 + i], a2[i]);
        }
        #pragma unroll
        for (int i = 0; i < 20; ++i) a2[i] = lrelu(a2[i]);
        // layer h3: [20] -> [2], lrelu.  Wh3 row-major [20][2].
        float nh0 = sbh3[0], nh1 = sbh3[1];
        #pragma unroll
        for (int i = 0; i < 20; ++i) {
            nh0 = fmaf(a2[i], sWh3[2 * i], nh0);
            nh1 = fmaf(a2[i], sWh3[2 * i + 1], nh1);
        }
        h0 = lrelu(nh0);
        h1 = lrelu(nh1);

        // ---- z path (uses the NEW h) ----
        float z1[50];
        #pragma unroll
        for (int j = 0; j < 50; ++j) {
            float v = fmaf(h1, sWz1[50 + j], fmaf(h0, sWz1[j], sbz1[j]));
            z1[j] = sigm(v);
        }
        float z2[20];
        #pragma unroll
        for (int i = 0; i < 20; ++i) z2[i] = sbz2[i];
        #pragma unroll
        for (int k = 0; k < 50; ++k) {
            const float zv = z1[k];
            #pragma unroll
            for (int i = 0; i < 20; ++i) z2[i] = fmaf(zv, sWz2[k * 20 + i], z2[i]);
        }
        #pragma unroll
        for (int i = 0; i < 20; ++i) z2[i] = sigm(z2[i]);
        float zo0 = sbz3[0], zo1 = sbz3[1];
        #pragma unroll
        for (int i = 0; i < 20; ++i) {
            zo0 = fmaf(z2[i], sWz3[2 * i], zo0);
            zo1 = fmaf(z2[i], sWz3[2 * i + 1], zo1);
        }
        zo0 = sigm(zo0);
        zo1 = sigm(zo1);

        // out[row][s][:] — 152 contiguous bytes per row; L2 write-combines.
        float2 o; o.x = zo0; o.y = zo1;
        *(float2*)(orow + 2 * s) = o;
    }
}

extern "C" void kernel_launch(void* const* d_in, const int* in_sizes, int n_in,
                              void* d_out, int out_size, void* d_ws, size_t ws_size,
                              hipStream_t stream) {
    const float* w   = (const float*)d_in[0];
    const float* Wh1 = (const float*)d_in[1];
    const float* bh1 = (const float*)d_in[2];
    const float* Wh2 = (const float*)d_in[3];
    const float* bh2 = (const float*)d_in[4];
    const float* Wh3 = (const float*)d_in[5];
    const float* bh3 = (const float*)d_in[6];
    const float* Wz1 = (const float*)d_in[7];
    const float* bz1 = (const float*)d_in[8];
    const float* Wz2 = (const float*)d_in[9];
    const float* bz2 = (const float*)d_in[10];
    const float* Wz3 = (const float*)d_in[11];
    const float* bz3 = (const float*)d_in[12];
    float* out = (float*)d_out;

    const int nrows = in_sizes[0] / 2;  // w is [B,2]
    const int blocks = (nrows + THREADS - 1) / THREADS;

    recurrent_kernel<<<blocks, THREADS, 0, stream>>>(
        w, Wh1, bh1, Wh2, bh2, Wh3, bh3,
        Wz1, bz1, Wz2, bz2, Wz3, bz3, out, nrows);
}